// Round 8
// baseline (293.134 us; speedup 1.0000x reference)
//
#include <hip/hip_runtime.h>

typedef __bf16 bf16;
typedef __bf16 bf16x2 __attribute__((ext_vector_type(2)));
typedef __bf16 bf16x4 __attribute__((ext_vector_type(4)));
typedef __bf16 bf16x8 __attribute__((ext_vector_type(8)));
typedef float f32x4 __attribute__((ext_vector_type(4)));

#define TT_ 2048
#define CC_ 1024
#define HH_ 64

// scale * 1/ln(2): softmax via exp2, no max subtraction (|s|<~3, fp32-safe).
// Folded into q at projection time (qb is pre-scaled by qkv_kernel).
#define SCALE2 0.045084221f

static __device__ __forceinline__ unsigned pack_bf16(float a, float b) {
    union { bf16x2 h; unsigned u; } z;
    z.h = bf16x2{(bf16)a, (bf16)b};
    return z.u;
}
// v_permlane32_swap_b32: a' = [a.lo32 | b.lo32], b' = [a.hi32 | b.hi32]
static __device__ __forceinline__ void plswap32(unsigned &a, unsigned &b) {
    asm("v_permlane32_swap_b32 %0, %1" : "+v"(a), "+v"(b));
}
// v_permlane16_swap_b32: odd 16-rows of a swap with even 16-rows of b
static __device__ __forceinline__ void plswap16(unsigned &a, unsigned &b) {
    asm("v_permlane16_swap_b32 %0, %1" : "+v"(a), "+v"(b));
}

// ---------------- prep: Wt[m][n][k] = W_m[k][n], fp32 -> bf16, LDS transpose --
__global__ __launch_bounds__(256) void prep_w(const float* __restrict__ Wq,
                                              const float* __restrict__ Wk,
                                              const float* __restrict__ Wv,
                                              bf16* __restrict__ Wt) {
    __shared__ bf16 Ls[64 * 65];
    const int m  = blockIdx.x >> 4;
    const int k0 = (blockIdx.x & 15) * 64;
    const float* W = (m == 0) ? Wq : (m == 1) ? Wk : Wv;
    const int tid = threadIdx.x;
    #pragma unroll
    for (int j = 0; j < 4; ++j) {
        int idx = tid + 256 * j;
        int r   = idx >> 4;
        int c4  = (idx & 15) * 4;
        float4 w = *(const float4*)&W[(size_t)(k0 + r) * HH_ + c4];
        Ls[r * 65 + c4 + 0] = (bf16)w.x;
        Ls[r * 65 + c4 + 1] = (bf16)w.y;
        Ls[r * 65 + c4 + 2] = (bf16)w.z;
        Ls[r * 65 + c4 + 3] = (bf16)w.w;
    }
    __syncthreads();
    #pragma unroll
    for (int j = 0; j < 4; ++j) {
        int idx = tid + 256 * j;
        int n   = idx >> 4;
        int kc  = (idx & 15) * 4;
        bf16x4 v;
        #pragma unroll
        for (int i = 0; i < 4; ++i) v[i] = Ls[(kc + i) * 65 + n];
        *(bf16x4*)&Wt[m * 65536 + n * 1024 + k0 + kc] = v;
    }
}

// ---------------- fused QKV projection ---------------------------------------
// Round 8: BARRIER-FREE K-loop with WAVE-PRIVATE LDS staging.
// r6 counters: barrier-lockstep left every pipe <13% busy. r7: removing LDS
// destroyed coalescing (16B/lane row-scatter). Fix: each wave stages its OWN
// copy of the 32x64 x-tile into a private LDS dbuf -- staged loads stay 256B
// coalesced; write->read is same-wave (lgkmcnt only, NO s_barrier). The 4x
// redundant x reads hit L1/L2 (16KB tile). T14 split: pf regs loaded ~2 tiles
// ahead, ds_write after the MFMAs. 2 barriers total (V-transpose epilogue).
// 32-row tiles, grid 1024 = 4 blocks/CU. q PRE-SCALED by SCALE2.
__global__ __launch_bounds__(256, 4) void qkv_kernel(const float* __restrict__ x,
                                                     const bf16* __restrict__ Wt,
                                                     bf16* __restrict__ qb,
                                                     bf16* __restrict__ kb,
                                                     bf16* __restrict__ vt) {
    __shared__ __align__(16) bf16 Xs[4][2][32 * 72];   // per-wave double buffer
    const int tid  = threadIdx.x;
    const int wave = tid >> 6;
    const int wl   = tid & 63;
    const int lane = tid & 15;
    const int quad = (tid & 63) >> 4;
    const int m0   = blockIdx.x * 32;

    bf16 (*myXs)[32 * 72] = Xs[wave];

    // staging: lane pair covers one row; 32 contiguous floats (128B) per lane
    const int srow = wl >> 1;
    const int scol = (wl & 1) * 32;
    const float* xsrc = x + (size_t)(m0 + srow) * CC_ + scol;
    const bf16*  wbase = Wt + (size_t)(wave * 48 + lane) * 1024 + quad * 8;

    f32x4 acc[2][3];
    #pragma unroll
    for (int i = 0; i < 2; ++i)
        #pragma unroll
        for (int j = 0; j < 3; ++j) acc[i][j] = f32x4{0.f, 0.f, 0.f, 0.f};

    float4 pf[8];
    // prologue: load tile 0, write buf 0; load tile 1 (kept in pf)
    #pragma unroll
    for (int i = 0; i < 8; ++i) pf[i] = *(const float4*)&xsrc[i * 4];
    #pragma unroll
    for (int i = 0; i < 4; ++i) {
        bf16x8 bv = {(bf16)pf[2*i].x, (bf16)pf[2*i].y, (bf16)pf[2*i].z, (bf16)pf[2*i].w,
                     (bf16)pf[2*i+1].x, (bf16)pf[2*i+1].y, (bf16)pf[2*i+1].z, (bf16)pf[2*i+1].w};
        *(bf16x8*)&myXs[0][srow * 72 + scol + i * 8] = bv;
    }
    #pragma unroll
    for (int i = 0; i < 8; ++i) pf[i] = *(const float4*)&xsrc[64 + i * 4];

    for (int kbi = 0; kbi < 16; ++kbi) {
        const int cur = kbi & 1;
        const int k0  = kbi * 64;
        // fragments for current tile (wave-private LDS; lgkmcnt only)
        bf16x8 afr[2][2];
        #pragma unroll
        for (int step = 0; step < 2; ++step)
            #pragma unroll
            for (int rt = 0; rt < 2; ++rt)
                afr[step][rt] = *(const bf16x8*)&myXs[cur][(rt * 16 + lane) * 72 + step * 32 + quad * 8];
        bf16x8 bfr[2][3];
        #pragma unroll
        for (int step = 0; step < 2; ++step)
            #pragma unroll
            for (int ct = 0; ct < 3; ++ct)
                bfr[step][ct] = *(const bf16x8*)&wbase[(size_t)(ct * 16) * 1024 + k0 + step * 32];
        #pragma unroll
        for (int step = 0; step < 2; ++step)
            #pragma unroll
            for (int ct = 0; ct < 3; ++ct)
                #pragma unroll
                for (int rt = 0; rt < 2; ++rt)
                    acc[rt][ct] = __builtin_amdgcn_mfma_f32_16x16x32_bf16(afr[step][rt], bfr[step][ct], acc[rt][ct], 0, 0, 0);
        // write prefetched tile kbi+1 into the other buffer (after MFMAs)
        if (kbi < 15) {
            #pragma unroll
            for (int i = 0; i < 4; ++i) {
                bf16x8 bv = {(bf16)pf[2*i].x, (bf16)pf[2*i].y, (bf16)pf[2*i].z, (bf16)pf[2*i].w,
                             (bf16)pf[2*i+1].x, (bf16)pf[2*i+1].y, (bf16)pf[2*i+1].z, (bf16)pf[2*i+1].w};
                *(bf16x8*)&myXs[cur ^ 1][srow * 72 + scol + i * 8] = bv;
            }
        }
        // issue loads for tile kbi+2 (in flight for ~a full iteration)
        if (kbi < 14) {
            #pragma unroll
            for (int i = 0; i < 8; ++i)
                pf[i] = *(const float4*)&xsrc[(kbi + 2) * 64 + i * 4];
        }
    }

    // epilogue: C/D layout col=lane, row=quad*4+r
    const int bb = m0 >> 11;
    const int t0 = m0 & 2047;
    __syncthreads();                  // waves are unsynced; Xs[0][0] reused below
    #pragma unroll
    for (int ct = 0; ct < 3; ++ct) {
        int c0 = wave * 48 + ct * 16;
        if (c0 < 64) {                          // q: pre-scaled by SCALE2
            int h = c0 + lane;
            #pragma unroll
            for (int rt = 0; rt < 2; ++rt)
                #pragma unroll
                for (int r = 0; r < 4; ++r)
                    qb[(size_t)(m0 + rt * 16 + quad * 4 + r) * HH_ + h] = (bf16)(acc[rt][ct][r] * SCALE2);
        } else if (c0 < 128) {                  // k
            int h = (c0 - 64) + lane;
            #pragma unroll
            for (int rt = 0; rt < 2; ++rt)
                #pragma unroll
                for (int r = 0; r < 4; ++r)
                    kb[(size_t)(m0 + rt * 16 + quad * 4 + r) * HH_ + h] = (bf16)acc[rt][ct][r];
        } else {                                // v -> LDS for transpose
            int h = (c0 - 128) + lane;
            #pragma unroll
            for (int rt = 0; rt < 2; ++rt)
                #pragma unroll
                for (int r = 0; r < 4; ++r)
                    Xs[0][0][(rt * 16 + quad * 4 + r) * 72 + h] = (bf16)acc[rt][ct][r];
        }
    }
    __syncthreads();
    {
        int h  = tid >> 2;
        int tc = (tid & 3) * 8;
        bf16x8 v0;
        #pragma unroll
        for (int i = 0; i < 8; ++i) v0[i] = Xs[0][0][(tc + i) * 72 + h];
        *(bf16x8*)&vt[(size_t)bb * HH_ * TT_ + (size_t)h * TT_ + t0 + tc] = v0;
    }
}

// ---------------- flash attention, non-split, direct output ------------------
// Round-5 version (best total). One block per (bb, qi): grid 512, 2 blocks/CU.
// Balance: bb = j&15, p = j>>4, qi = (p<16) ? p : 47-p.
// Row-sums via a 5th MFMA with all-ones B; normalize in-register; fp32 out.
__global__ __launch_bounds__(256, 2) void attn_kernel(const bf16* __restrict__ qb,
                                                      const bf16* __restrict__ kb,
                                                      const bf16* __restrict__ vt,
                                                      float* __restrict__ out) {
    __shared__ __align__(16) bf16 Ks[128 * 72];
    __shared__ __align__(16) bf16 Vs[64 * 136];

    const int tid  = threadIdx.x;
    const int wave = tid >> 6;
    const int lane = tid & 15;
    const int quad = (tid & 63) >> 4;

    const int j  = blockIdx.x;
    const int bb = j & 15;
    const int p  = j >> 4;
    const int qi = (p < 16) ? p : 47 - p;
    const int nch = (qi >> 1) + 1;          // chunks of 128 keys, incl. diag

    const int qrow  = qi * 64 + wave * 16;
    const int qg    = qrow + lane;          // this lane's q row
    const int qmaxw = qrow + 15;            // max q row in this wave

    // staging assignments (per-thread constants)
    const int krow = tid >> 3, kc8 = (tid & 7) * 8;       // K: 128 x 64h
    const int vh   = tid >> 4, vc8 = (tid & 15) * 8;      // V^T: 64h x 128s
    const bf16* kp = kb + (size_t)(bb * TT_ + krow) * HH_ + kc8;
    const bf16* vp = vt + (size_t)bb * HH_ * TT_ + (size_t)vh * TT_ + vc8;

    // prologue: issue chunk-0 loads
    bf16x8 kr[4], vvr[4];
    #pragma unroll
    for (int j2 = 0; j2 < 4; ++j2) kr[j2]  = *(const bf16x8*)&kp[(size_t)j2 * 32 * HH_];
    #pragma unroll
    for (int j2 = 0; j2 < 4; ++j2) vvr[j2] = *(const bf16x8*)&vp[j2 * 16 * TT_];

    // Q fragment (B operand): lane -> q col, quad*8 -> h  (pre-scaled)
    bf16x8 aq[2];
    #pragma unroll
    for (int step = 0; step < 2; ++step)
        aq[step] = *(const bf16x8*)&qb[(size_t)(bb * TT_ + qg) * HH_ + step * 32 + quad * 8];

    // all-ones B fragment for the row-sum MFMA
    bf16x8 vones;
    #pragma unroll
    for (int i = 0; i < 8; ++i) vones[i] = (bf16)1.0f;

    f32x4 o_acc[4];
    #pragma unroll
    for (int ht = 0; ht < 4; ++ht) o_acc[ht] = f32x4{0.f, 0.f, 0.f, 0.f};
    f32x4 lacc = f32x4{0.f, 0.f, 0.f, 0.f};

    for (int c = 0; c < nch; ++c) {
        const int s0 = c * 128;
        __syncthreads();                 // all waves done computing chunk c-1
        #pragma unroll
        for (int j2 = 0; j2 < 4; ++j2) *(bf16x8*)&Ks[(krow + 32 * j2) * 72 + kc8] = kr[j2];
        #pragma unroll
        for (int j2 = 0; j2 < 4; ++j2) *(bf16x8*)&Vs[(vh + 16 * j2) * 136 + vc8]  = vvr[j2];
        __syncthreads();
        if (c + 1 < nch) {               // issue next chunk's loads early
            #pragma unroll
            for (int j2 = 0; j2 < 4; ++j2)
                kr[j2] = *(const bf16x8*)&kp[(size_t)((c + 1) * 128 + j2 * 32) * HH_];
            #pragma unroll
            for (int j2 = 0; j2 < 4; ++j2)
                vvr[j2] = *(const bf16x8*)&vp[(c + 1) * 128 + j2 * 16 * TT_];
        }

        const bool msk = (c == nch - 1);
        #pragma unroll
        for (int w = 0; w < 4; ++w) {       // 4 windows of 32 keys
            if (msk && (s0 + w * 32 > qmaxw)) continue;       // wave-uniform
            const bool haveB = !msk || (s0 + w * 32 + 16 <= qmaxw);

            // QK^T (swapped): s[key=tile+quad*4+r][q=qg]
            f32x4 sA = {0.f, 0.f, 0.f, 0.f};
            f32x4 sB = {0.f, 0.f, 0.f, 0.f};
            __builtin_amdgcn_s_setprio(1);
            {
                bf16x8 ak0 = *(const bf16x8*)&Ks[(w * 32 + lane) * 72 + quad * 8];
                bf16x8 ak1 = *(const bf16x8*)&Ks[(w * 32 + lane) * 72 + 32 + quad * 8];
                sA = __builtin_amdgcn_mfma_f32_16x16x32_bf16(ak0, aq[0], sA, 0, 0, 0);
                sA = __builtin_amdgcn_mfma_f32_16x16x32_bf16(ak1, aq[1], sA, 0, 0, 0);
            }
            if (haveB) {
                bf16x8 bk0 = *(const bf16x8*)&Ks[(w * 32 + 16 + lane) * 72 + quad * 8];
                bf16x8 bk1 = *(const bf16x8*)&Ks[(w * 32 + 16 + lane) * 72 + 32 + quad * 8];
                sB = __builtin_amdgcn_mfma_f32_16x16x32_bf16(bk0, aq[0], sB, 0, 0, 0);
                sB = __builtin_amdgcn_mfma_f32_16x16x32_bf16(bk1, aq[1], sB, 0, 0, 0);
            }
            __builtin_amdgcn_s_setprio(0);

            // softmax (in-register, max-free; scale pre-folded into q)
            const int kA0 = s0 + w * 32 + quad * 4;
            float eA[4], eB[4];
            #pragma unroll
            for (int r = 0; r < 4; ++r) {
                float e = __builtin_amdgcn_exp2f(sA[r]);
                if (msk && (kA0 + r > qg)) e = 0.f;
                eA[r] = e;
            }
            if (haveB) {
                #pragma unroll
                for (int r = 0; r < 4; ++r) {
                    float e = __builtin_amdgcn_exp2f(sB[r]);
                    if (msk && (kA0 + 16 + r > qg)) e = 0.f;
                    eB[r] = e;
                }
            } else {
                #pragma unroll
                for (int r = 0; r < 4; ++r) eB[r] = 0.f;
            }

            // P: C-layout -> 16x16x32 A-layout, all in registers
            unsigned d0 = pack_bf16(eA[0], eA[1]);
            unsigned d1 = pack_bf16(eA[2], eA[3]);
            unsigned d2 = pack_bf16(eB[0], eB[1]);
            unsigned d3 = pack_bf16(eB[2], eB[3]);
            plswap32(d0, d2);
            plswap16(d0, d2);
            plswap32(d1, d3);
            plswap16(d1, d3);
            union { unsigned u[4]; bf16x8 v; } apu;
            apu.u[0] = d0; apu.u[1] = d1; apu.u[2] = d2; apu.u[3] = d3;

            // PV + row-sum: x32 MFMA straight from registers + Vs
            __builtin_amdgcn_s_setprio(1);
            #pragma unroll
            for (int ht = 0; ht < 4; ++ht) {
                bf16x8 bv = *(const bf16x8*)&Vs[(ht * 16 + lane) * 136 + w * 32 + quad * 8];
                o_acc[ht] = __builtin_amdgcn_mfma_f32_16x16x32_bf16(apu.v, bv, o_acc[ht], 0, 0, 0);
            }
            lacc = __builtin_amdgcn_mfma_f32_16x16x32_bf16(apu.v, vones, lacc, 0, 0, 0);
            __builtin_amdgcn_s_setprio(0);
        }
    }

    // epilogue: normalize and write fp32 output directly.
    // o_acc[ht][r]: row q = qrow + quad*4 + r, col h = ht*16 + lane.
    // lacc[r] = rowsum for the SAME q (all 16 cols identical).
    float inv[4];
    #pragma unroll
    for (int r = 0; r < 4; ++r) inv[r] = __builtin_amdgcn_rcpf(lacc[r]);
    #pragma unroll
    for (int ht = 0; ht < 4; ++ht)
        #pragma unroll
        for (int r = 0; r < 4; ++r)
            out[(size_t)(bb * TT_ + qrow + quad * 4 + r) * HH_ + ht * 16 + lane] = o_acc[ht][r] * inv[r];
}

extern "C" void kernel_launch(void* const* d_in, const int* in_sizes, int n_in,
                              void* d_out, int out_size, void* d_ws, size_t ws_size,
                              hipStream_t stream) {
    const float* x  = (const float*)d_in[0];
    const float* Wq = (const float*)d_in[1];
    const float* Wk = (const float*)d_in[2];
    const float* Wv = (const float*)d_in[3];
    float* out = (float*)d_out;

    char* ws = (char*)d_ws;
    bf16*  qb = (bf16*)(ws);                       // 4 MiB (pre-scaled q)
    bf16*  kb = (bf16*)(ws + 4194304);             // 4 MiB
    bf16*  vt = (bf16*)(ws + 8388608);             // 4 MiB  V^T [bb][h][t]
    bf16*  Wt = (bf16*)(ws + 12582912);            // 384 KiB

    prep_w<<<48, 256, 0, stream>>>(Wq, Wk, Wv, Wt);
    qkv_kernel<<<1024, 256, 0, stream>>>(x, Wt, qb, kb, vt);
    attn_kernel<<<512, 256, 0, stream>>>(qb, kb, vt, out);
}

// Round 9
// 251.737 us; speedup vs baseline: 1.1644x; 1.1644x over previous
//
#include <hip/hip_runtime.h>

typedef __bf16 bf16;
typedef __bf16 bf16x2 __attribute__((ext_vector_type(2)));
typedef __bf16 bf16x4 __attribute__((ext_vector_type(4)));
typedef __bf16 bf16x8 __attribute__((ext_vector_type(8)));
typedef float f32x4 __attribute__((ext_vector_type(4)));

#define TT_ 2048
#define CC_ 1024
#define HH_ 64

// scale * 1/ln(2): softmax via exp2, no max subtraction (|s|<~3, fp32-safe).
// Folded into q at projection time (qb is pre-scaled by qkv_kernel).
#define SCALE2 0.045084221f

static __device__ __forceinline__ unsigned pack_bf16(float a, float b) {
    union { bf16x2 h; unsigned u; } z;
    z.h = bf16x2{(bf16)a, (bf16)b};
    return z.u;
}
// v_permlane32_swap_b32: a' = [a.lo32 | b.lo32], b' = [a.hi32 | b.hi32]
static __device__ __forceinline__ void plswap32(unsigned &a, unsigned &b) {
    asm("v_permlane32_swap_b32 %0, %1" : "+v"(a), "+v"(b));
}
// v_permlane16_swap_b32: odd 16-rows of a swap with even 16-rows of b
static __device__ __forceinline__ void plswap16(unsigned &a, unsigned &b) {
    asm("v_permlane16_swap_b32 %0, %1" : "+v"(a), "+v"(b));
}

// ---------------- prep: Wt[m][n][k] = W_m[k][n], fp32 -> bf16, LDS transpose --
__global__ __launch_bounds__(256) void prep_w(const float* __restrict__ Wq,
                                              const float* __restrict__ Wk,
                                              const float* __restrict__ Wv,
                                              bf16* __restrict__ Wt) {
    __shared__ bf16 Ls[64 * 65];
    const int m  = blockIdx.x >> 4;
    const int k0 = (blockIdx.x & 15) * 64;
    const float* W = (m == 0) ? Wq : (m == 1) ? Wk : Wv;
    const int tid = threadIdx.x;
    #pragma unroll
    for (int j = 0; j < 4; ++j) {
        int idx = tid + 256 * j;
        int r   = idx >> 4;
        int c4  = (idx & 15) * 4;
        float4 w = *(const float4*)&W[(size_t)(k0 + r) * HH_ + c4];
        Ls[r * 65 + c4 + 0] = (bf16)w.x;
        Ls[r * 65 + c4 + 1] = (bf16)w.y;
        Ls[r * 65 + c4 + 2] = (bf16)w.z;
        Ls[r * 65 + c4 + 3] = (bf16)w.w;
    }
    __syncthreads();
    #pragma unroll
    for (int j = 0; j < 4; ++j) {
        int idx = tid + 256 * j;
        int n   = idx >> 4;
        int kc  = (idx & 15) * 4;
        bf16x4 v;
        #pragma unroll
        for (int i = 0; i < 4; ++i) v[i] = Ls[(kc + i) * 65 + n];
        *(bf16x4*)&Wt[m * 65536 + n * 1024 + k0 + kc] = v;
    }
}

// ---------------- fused QKV projection ---------------------------------------
// Round 9: global_load_lds staging (Common-mistake #1 -- never tried yet).
// x tile (32x64 fp32) staged DIRECTLY into LDS: no VGPR landing, no ds_write,
// no drain-before-write. Loop: issue glds(t+1, buf^1) -> ds_read+cvt+MFMA on
// buf -> __syncthreads (its vmcnt(0) drain is the ONLY wait, after ~400cy of
// compute). ONE barrier/iter. LDS linear [32][64] fp32 (glds can't scatter);
// 16-way read conflict fixed per rule #21: involution XOR swizzle applied to
// the GLOBAL source slot (slot ^= (row&7)<<1) and the same XOR on the read.
// Staging stays coalesced (permutation within each 256B row). bf16 cast moves
// after the LDS read. 32-row tiles, grid 1024 = 4 blocks/CU, LDS 16.4 KB.
__global__ __launch_bounds__(256, 4) void qkv_kernel(const float* __restrict__ x,
                                                     const bf16* __restrict__ Wt,
                                                     bf16* __restrict__ qb,
                                                     bf16* __restrict__ kb,
                                                     bf16* __restrict__ vt) {
    __shared__ __align__(16) float XsF[2][32 * 64];
    const int tid  = threadIdx.x;
    const int wave = tid >> 6;
    const int wl   = tid & 63;
    const int lane = tid & 15;
    const int quad = wl >> 4;
    const int m0   = blockIdx.x * 32;

    // staging: wave w stages rows w*8..w*8+7; instr i covers 4 rows.
    // lane l -> row (l>>4), 16B slot (l&15); global slot pre-swizzled.
    const int rr = wl >> 4;
    const int sl = wl & 15;
    const float* gsrc[2];
    #pragma unroll
    for (int i = 0; i < 2; ++i) {
        int row = wave * 8 + i * 4 + rr;              // row in tile (0..31)
        int e   = (row & 7) << 1;                     // even XOR -> involution
        gsrc[i] = x + (size_t)(m0 + row) * CC_ + ((sl ^ e) << 2);
    }

    const bf16* wbase = Wt + (size_t)(wave * 48 + lane) * 1024 + quad * 8;

    f32x4 acc[2][3];
    #pragma unroll
    for (int i = 0; i < 2; ++i)
        #pragma unroll
        for (int j = 0; j < 3; ++j) acc[i][j] = f32x4{0.f, 0.f, 0.f, 0.f};

    // prologue: stage tile 0 into buf 0
    #pragma unroll
    for (int i = 0; i < 2; ++i)
        __builtin_amdgcn_global_load_lds(
            (const __attribute__((address_space(1))) void*)(gsrc[i]),
            (__attribute__((address_space(3))) void*)(&XsF[0][(wave * 8 + i * 4) * 64]),
            16, 0, 0);
    __syncthreads();

    for (int kbi = 0; kbi < 16; ++kbi) {
        const int cur = kbi & 1;
        const int k0  = kbi * 64;
        // issue next tile's async loads first (land during this tile's MFMAs)
        if (kbi < 15) {
            #pragma unroll
            for (int i = 0; i < 2; ++i)
                __builtin_amdgcn_global_load_lds(
                    (const __attribute__((address_space(1))) void*)(gsrc[i] + (kbi + 1) * 64),
                    (__attribute__((address_space(3))) void*)(&XsF[cur ^ 1][(wave * 8 + i * 4) * 64]),
                    16, 0, 0);
        }
        // A fragments: swizzled fp32 LDS reads + cvt to bf16
        bf16x8 afr[2][2];
        #pragma unroll
        for (int step = 0; step < 2; ++step)
            #pragma unroll
            for (int rt = 0; rt < 2; ++rt) {
                int row = rt * 16 + lane;
                int s0  = (step * 8 + quad * 2) ^ ((lane & 7) << 1);
                const float* p = &XsF[cur][row * 64 + s0 * 4];
                float4 a = *(const float4*)p;
                float4 b = *(const float4*)(p + 4);
                afr[step][rt] = bf16x8{(bf16)a.x, (bf16)a.y, (bf16)a.z, (bf16)a.w,
                                       (bf16)b.x, (bf16)b.y, (bf16)b.z, (bf16)b.w};
            }
        // B fragments: Wt from L2
        bf16x8 bfr[2][3];
        #pragma unroll
        for (int step = 0; step < 2; ++step)
            #pragma unroll
            for (int ct = 0; ct < 3; ++ct)
                bfr[step][ct] = *(const bf16x8*)&wbase[(size_t)(ct * 16) * 1024 + k0 + step * 32];
        #pragma unroll
        for (int step = 0; step < 2; ++step)
            #pragma unroll
            for (int ct = 0; ct < 3; ++ct)
                #pragma unroll
                for (int rt = 0; rt < 2; ++rt)
                    acc[rt][ct] = __builtin_amdgcn_mfma_f32_16x16x32_bf16(afr[step][rt], bfr[step][ct], acc[rt][ct], 0, 0, 0);
        __syncthreads();   // vmcnt(0) drain (next tile landed) + wave sync
    }

    // epilogue: C/D layout col=lane, row=quad*4+r
    const int bb = m0 >> 11;
    const int t0 = m0 & 2047;
    bf16* Vb = (bf16*)&XsF[0][0];        // reuse buf0 (4.6 KB of 8 KB)
    #pragma unroll
    for (int ct = 0; ct < 3; ++ct) {
        int c0 = wave * 48 + ct * 16;
        if (c0 < 64) {                          // q: pre-scaled by SCALE2
            int h = c0 + lane;
            #pragma unroll
            for (int rt = 0; rt < 2; ++rt)
                #pragma unroll
                for (int r = 0; r < 4; ++r)
                    qb[(size_t)(m0 + rt * 16 + quad * 4 + r) * HH_ + h] = (bf16)(acc[rt][ct][r] * SCALE2);
        } else if (c0 < 128) {                  // k
            int h = (c0 - 64) + lane;
            #pragma unroll
            for (int rt = 0; rt < 2; ++rt)
                #pragma unroll
                for (int r = 0; r < 4; ++r)
                    kb[(size_t)(m0 + rt * 16 + quad * 4 + r) * HH_ + h] = (bf16)acc[rt][ct][r];
        } else {                                // v -> LDS for transpose
            int h = (c0 - 128) + lane;
            #pragma unroll
            for (int rt = 0; rt < 2; ++rt)
                #pragma unroll
                for (int r = 0; r < 4; ++r)
                    Vb[(rt * 16 + quad * 4 + r) * 72 + h] = (bf16)acc[rt][ct][r];
        }
    }
    __syncthreads();
    {
        int h  = tid >> 2;
        int tc = (tid & 3) * 8;
        bf16x8 v0;
        #pragma unroll
        for (int i = 0; i < 8; ++i) v0[i] = Vb[(tc + i) * 72 + h];
        *(bf16x8*)&vt[(size_t)bb * HH_ * TT_ + (size_t)h * TT_ + t0 + tc] = v0;
    }
}

// ---------------- flash attention, non-split, direct output ------------------
// Round-5 version (best total). One block per (bb, qi): grid 512, 2 blocks/CU.
// Balance: bb = j&15, p = j>>4, qi = (p<16) ? p : 47-p.
// Row-sums via a 5th MFMA with all-ones B; normalize in-register; fp32 out.
__global__ __launch_bounds__(256, 2) void attn_kernel(const bf16* __restrict__ qb,
                                                      const bf16* __restrict__ kb,
                                                      const bf16* __restrict__ vt,
                                                      float* __restrict__ out) {
    __shared__ __align__(16) bf16 Ks[128 * 72];
    __shared__ __align__(16) bf16 Vs[64 * 136];

    const int tid  = threadIdx.x;
    const int wave = tid >> 6;
    const int lane = tid & 15;
    const int quad = (tid & 63) >> 4;

    const int j  = blockIdx.x;
    const int bb = j & 15;
    const int p  = j >> 4;
    const int qi = (p < 16) ? p : 47 - p;
    const int nch = (qi >> 1) + 1;          // chunks of 128 keys, incl. diag

    const int qrow  = qi * 64 + wave * 16;
    const int qg    = qrow + lane;          // this lane's q row
    const int qmaxw = qrow + 15;            // max q row in this wave

    // staging assignments (per-thread constants)
    const int krow = tid >> 3, kc8 = (tid & 7) * 8;       // K: 128 x 64h
    const int vh   = tid >> 4, vc8 = (tid & 15) * 8;      // V^T: 64h x 128s
    const bf16* kp = kb + (size_t)(bb * TT_ + krow) * HH_ + kc8;
    const bf16* vp = vt + (size_t)bb * HH_ * TT_ + (size_t)vh * TT_ + vc8;

    // prologue: issue chunk-0 loads
    bf16x8 kr[4], vvr[4];
    #pragma unroll
    for (int j2 = 0; j2 < 4; ++j2) kr[j2]  = *(const bf16x8*)&kp[(size_t)j2 * 32 * HH_];
    #pragma unroll
    for (int j2 = 0; j2 < 4; ++j2) vvr[j2] = *(const bf16x8*)&vp[j2 * 16 * TT_];

    // Q fragment (B operand): lane -> q col, quad*8 -> h  (pre-scaled)
    bf16x8 aq[2];
    #pragma unroll
    for (int step = 0; step < 2; ++step)
        aq[step] = *(const bf16x8*)&qb[(size_t)(bb * TT_ + qg) * HH_ + step * 32 + quad * 8];

    // all-ones B fragment for the row-sum MFMA
    bf16x8 vones;
    #pragma unroll
    for (int i = 0; i < 8; ++i) vones[i] = (bf16)1.0f;

    f32x4 o_acc[4];
    #pragma unroll
    for (int ht = 0; ht < 4; ++ht) o_acc[ht] = f32x4{0.f, 0.f, 0.f, 0.f};
    f32x4 lacc = f32x4{0.f, 0.f, 0.f, 0.f};

    for (int c = 0; c < nch; ++c) {
        const int s0 = c * 128;
        __syncthreads();                 // all waves done computing chunk c-1
        #pragma unroll
        for (int j2 = 0; j2 < 4; ++j2) *(bf16x8*)&Ks[(krow + 32 * j2) * 72 + kc8] = kr[j2];
        #pragma unroll
        for (int j2 = 0; j2 < 4; ++j2) *(bf16x8*)&Vs[(vh + 16 * j2) * 136 + vc8]  = vvr[j2];
        __syncthreads();
        if (c + 1 < nch) {               // issue next chunk's loads early
            #pragma unroll
            for (int j2 = 0; j2 < 4; ++j2)
                kr[j2] = *(const bf16x8*)&kp[(size_t)((c + 1) * 128 + j2 * 32) * HH_];
            #pragma unroll
            for (int j2 = 0; j2 < 4; ++j2)
                vvr[j2] = *(const bf16x8*)&vp[(c + 1) * 128 + j2 * 16 * TT_];
        }

        const bool msk = (c == nch - 1);
        #pragma unroll
        for (int w = 0; w < 4; ++w) {       // 4 windows of 32 keys
            if (msk && (s0 + w * 32 > qmaxw)) continue;       // wave-uniform
            const bool haveB = !msk || (s0 + w * 32 + 16 <= qmaxw);

            // QK^T (swapped): s[key=tile+quad*4+r][q=qg]
            f32x4 sA = {0.f, 0.f, 0.f, 0.f};
            f32x4 sB = {0.f, 0.f, 0.f, 0.f};
            __builtin_amdgcn_s_setprio(1);
            {
                bf16x8 ak0 = *(const bf16x8*)&Ks[(w * 32 + lane) * 72 + quad * 8];
                bf16x8 ak1 = *(const bf16x8*)&Ks[(w * 32 + lane) * 72 + 32 + quad * 8];
                sA = __builtin_amdgcn_mfma_f32_16x16x32_bf16(ak0, aq[0], sA, 0, 0, 0);
                sA = __builtin_amdgcn_mfma_f32_16x16x32_bf16(ak1, aq[1], sA, 0, 0, 0);
            }
            if (haveB) {
                bf16x8 bk0 = *(const bf16x8*)&Ks[(w * 32 + 16 + lane) * 72 + quad * 8];
                bf16x8 bk1 = *(const bf16x8*)&Ks[(w * 32 + 16 + lane) * 72 + 32 + quad * 8];
                sB = __builtin_amdgcn_mfma_f32_16x16x32_bf16(bk0, aq[0], sB, 0, 0, 0);
                sB = __builtin_amdgcn_mfma_f32_16x16x32_bf16(bk1, aq[1], sB, 0, 0, 0);
            }
            __builtin_amdgcn_s_setprio(0);

            // softmax (in-register, max-free; scale pre-folded into q)
            const int kA0 = s0 + w * 32 + quad * 4;
            float eA[4], eB[4];
            #pragma unroll
            for (int r = 0; r < 4; ++r) {
                float e = __builtin_amdgcn_exp2f(sA[r]);
                if (msk && (kA0 + r > qg)) e = 0.f;
                eA[r] = e;
            }
            if (haveB) {
                #pragma unroll
                for (int r = 0; r < 4; ++r) {
                    float e = __builtin_amdgcn_exp2f(sB[r]);
                    if (msk && (kA0 + 16 + r > qg)) e = 0.f;
                    eB[r] = e;
                }
            } else {
                #pragma unroll
                for (int r = 0; r < 4; ++r) eB[r] = 0.f;
            }

            // P: C-layout -> 16x16x32 A-layout, all in registers
            unsigned d0 = pack_bf16(eA[0], eA[1]);
            unsigned d1 = pack_bf16(eA[2], eA[3]);
            unsigned d2 = pack_bf16(eB[0], eB[1]);
            unsigned d3 = pack_bf16(eB[2], eB[3]);
            plswap32(d0, d2);
            plswap16(d0, d2);
            plswap32(d1, d3);
            plswap16(d1, d3);
            union { unsigned u[4]; bf16x8 v; } apu;
            apu.u[0] = d0; apu.u[1] = d1; apu.u[2] = d2; apu.u[3] = d3;

            // PV + row-sum: x32 MFMA straight from registers + Vs
            __builtin_amdgcn_s_setprio(1);
            #pragma unroll
            for (int ht = 0; ht < 4; ++ht) {
                bf16x8 bv = *(const bf16x8*)&Vs[(ht * 16 + lane) * 136 + w * 32 + quad * 8];
                o_acc[ht] = __builtin_amdgcn_mfma_f32_16x16x32_bf16(apu.v, bv, o_acc[ht], 0, 0, 0);
            }
            lacc = __builtin_amdgcn_mfma_f32_16x16x32_bf16(apu.v, vones, lacc, 0, 0, 0);
            __builtin_amdgcn_s_setprio(0);
        }
    }

    // epilogue: normalize and write fp32 output directly.
    // o_acc[ht][r]: row q = qrow + quad*4 + r, col h = ht*16 + lane.
    // lacc[r] = rowsum for the SAME q (all 16 cols identical).
    float inv[4];
    #pragma unroll
    for (int r = 0; r < 4; ++r) inv[r] = __builtin_amdgcn_rcpf(lacc[r]);
    #pragma unroll
    for (int ht = 0; ht < 4; ++ht)
        #pragma unroll
        for (int r = 0; r < 4; ++r)
            out[(size_t)(bb * TT_ + qrow + quad * 4 + r) * HH_ + ht * 16 + lane] = o_acc[ht][r] * inv[r];
}

extern "C" void kernel_launch(void* const* d_in, const int* in_sizes, int n_in,
                              void* d_out, int out_size, void* d_ws, size_t ws_size,
                              hipStream_t stream) {
    const float* x  = (const float*)d_in[0];
    const float* Wq = (const float*)d_in[1];
    const float* Wk = (const float*)d_in[2];
    const float* Wv = (const float*)d_in[3];
    float* out = (float*)d_out;

    char* ws = (char*)d_ws;
    bf16*  qb = (bf16*)(ws);                       // 4 MiB (pre-scaled q)
    bf16*  kb = (bf16*)(ws + 4194304);             // 4 MiB
    bf16*  vt = (bf16*)(ws + 8388608);             // 4 MiB  V^T [bb][h][t]
    bf16*  Wt = (bf16*)(ws + 12582912);            // 384 KiB

    prep_w<<<48, 256, 0, stream>>>(Wq, Wk, Wv, Wt);
    qkv_kernel<<<1024, 256, 0, stream>>>(x, Wt, qb, kb, vt);
    attn_kernel<<<512, 256, 0, stream>>>(qb, kb, vt, out);
}